// Round 3
// baseline (1776.796 us; speedup 1.0000x reference)
//
#include <hip/hip_runtime.h>

// HalfEdgeMeshPool: segment-mean of half-edge features into surviving groups.
// feat: [B, C, N] f32, gid: [B, N] i32 in [0,T), out: [B, C, T] f32.
//
// Strategy: LDS f32 atomics measured at ~3.2 cyc/lane per CU (occupancy-
// independent) -> eliminate scatter entirely. Counting-sort half-edges by
// group once per mesh b (counts -> scan -> perm), then each pool thread owns
// an exclusive t-range and gathers its members: no atomics in the hot path.
static constexpr int B = 8;
static constexpr int C = 256;
static constexpr int N = 40000;
static constexpr int T = 20000;
static constexpr int G = 16;  // groups per pool thread (exclusive ownership)

// ---- Phase 1: per-(b,t) member counts (320K int atomics, trivial) ----
__global__ void __launch_bounds__(256) hemp_count_kernel(const int* __restrict__ gid,
                                                         int* __restrict__ counts) {
    int idx = blockIdx.x * 256 + threadIdx.x;  // grid exactly B*N/256
    int b = idx / N;
    atomicAdd(&counts[b * T + gid[idx]], 1);
}

// ---- Phase 2: per-b exclusive scan counts -> row_ptr [B][T+1] ----
__global__ void __launch_bounds__(1024) hemp_scan_kernel(const int* __restrict__ counts,
                                                         int* __restrict__ rp) {
    const int b = blockIdx.x;
    __shared__ int wsum[16];
    __shared__ int carry_s;
    __shared__ int chunk_total_s;
    const int tid = threadIdx.x;
    const int lane = tid & 63;
    const int wv = tid >> 6;
    if (tid == 0) carry_s = 0;
    __syncthreads();
    for (int base = 0; base < T; base += 1024) {
        int i = base + tid;
        int x = (i < T) ? counts[b * T + i] : 0;
        int inc = x;
        #pragma unroll
        for (int off = 1; off < 64; off <<= 1) {
            int y = __shfl_up(inc, off);
            if (lane >= off) inc += y;
        }
        if (lane == 63) wsum[wv] = inc;
        __syncthreads();
        if (wv == 0 && lane < 16) {
            int w = wsum[lane];
            int winc = w;
            #pragma unroll
            for (int off = 1; off < 16; off <<= 1) {
                int y = __shfl_up(winc, off);
                if (lane >= off) winc += y;
            }
            wsum[lane] = winc - w;                 // exclusive wave prefix
            if (lane == 15) chunk_total_s = winc;  // chunk total
        }
        __syncthreads();
        int excl = carry_s + wsum[wv] + (inc - x);
        if (i < T) rp[b * (T + 1) + i] = excl;
        __syncthreads();
        if (tid == 0) carry_s += chunk_total_s;
        __syncthreads();
    }
    if (tid == 0) rp[b * (T + 1) + T] = carry_s;  // == N
}

// ---- Phase 3: head[b][t] = rp[b][t] (bump pointers for the fill) ----
__global__ void __launch_bounds__(256) hemp_head_kernel(const int* __restrict__ rp,
                                                        int* __restrict__ head) {
    int i = blockIdx.x * 256 + threadIdx.x;  // grid exactly B*T/256
    int b = i / T;
    int t = i - b * T;
    head[i] = rp[b * (T + 1) + t];
}

// ---- Phase 4: scatter n into perm (sorted-by-gid order) ----
__global__ void __launch_bounds__(256) hemp_fill_kernel(const int* __restrict__ gid,
                                                        int* __restrict__ head,
                                                        int* __restrict__ perm) {
    int idx = blockIdx.x * 256 + threadIdx.x;  // grid exactly B*N/256
    int b = idx / N;
    int n = idx - b * N;
    int g = gid[idx];
    int pos = atomicAdd(&head[b * T + g], 1);
    perm[(size_t)b * N + pos] = n;
}

// ---- Phase 5: exclusive gather-mean. One thread owns G groups; no atomics. ----
static constexpr int SLOTS = (T + G - 1) / G;                 // 1250
static constexpr int BLKS_PER_BC = (SLOTS + 255) / 256;       // 5
__global__ void __launch_bounds__(256) hemp_pool_kernel(const float* __restrict__ feat,
                                                        const int* __restrict__ rp,
                                                        const int* __restrict__ perm,
                                                        float* __restrict__ out) {
    const int bc = blockIdx.x / BLKS_PER_BC;
    const int sb = blockIdx.x - bc * BLKS_PER_BC;
    const int b = bc >> 8;
    const int c = bc & 255;
    const int slot = sb * 256 + threadIdx.x;
    int t0 = slot * G;
    if (t0 >= T) return;
    const int tend = min(t0 + G, T);

    const float* __restrict__ frow = feat + (size_t)(b * C + c) * N;
    const int* __restrict__ rpb = rp + (size_t)b * (T + 1);
    const int* __restrict__ permb = perm + (size_t)b * N;
    float* __restrict__ orow = out + (size_t)(b * C + c) * T;

    int j = rpb[t0];
    for (int t = t0; t < tend; ++t) {
        const int je = rpb[t + 1];
        const int cnt = je - j;
        float s = 0.0f;
        for (; j < je; ++j) s += frow[permb[j]];
        orow[t] = s / fmaxf((float)cnt, 1.0f);
    }
}

extern "C" void kernel_launch(void* const* d_in, const int* in_sizes, int n_in,
                              void* d_out, int out_size, void* d_ws, size_t ws_size,
                              hipStream_t stream) {
    const float* feat = (const float*)d_in[0];
    const int* gid = (const int*)d_in[1];
    float* out = (float*)d_out;

    // ws layout (~3.2 MB total)
    int* counts = (int*)d_ws;                 // B*T
    int* rp = counts + (size_t)B * T;         // B*(T+1)
    int* head = rp + (size_t)B * (T + 1);     // B*T
    int* perm = head + (size_t)B * T;         // B*N

    hipMemsetAsync(counts, 0, (size_t)B * T * sizeof(int), stream);
    hemp_count_kernel<<<B * N / 256, 256, 0, stream>>>(gid, counts);
    hemp_scan_kernel<<<B, 1024, 0, stream>>>(counts, rp);
    hemp_head_kernel<<<B * T / 256, 256, 0, stream>>>(rp, head);
    hemp_fill_kernel<<<B * N / 256, 256, 0, stream>>>(gid, head, perm);
    hemp_pool_kernel<<<B * C * BLKS_PER_BC, 256, 0, stream>>>(feat, rp, perm, out);
}

// Round 4
// 308.451 us; speedup vs baseline: 5.7604x; 5.7604x over previous
//
#include <hip/hip_runtime.h>

// HalfEdgeMeshPool: segment-mean over groups.
// feat: [B, C, N] f32, gid: [B, N] i32 in [0,T), out: [B, C, T] f32.
//
// R1/R2: LDS f32 atomics = serialized ~3.2 cyc/lane (occupancy-independent) -> 428us floor.
// R3: random 4B global gather = 14.5x line over-fetch (4.7GB) -> 1.7ms.
// R4: all-streaming pipeline. Counting-sort gid (cheap), transpose feat to
// [B,N,C] bf16 (line-granular rows per half-edge), then exclusive per-group
// gather of contiguous 512B member rows. No atomics / no sub-line access in hot path.
static constexpr int B = 8;
static constexpr int C = 256;
static constexpr int N = 40000;
static constexpr int T = 20000;
static constexpr int GT = 32;   // groups per pool block

// ---- counting sort: per-(b,t) member counts (int4-vectorized) ----
__global__ void __launch_bounds__(256) hemp_count_kernel(const int* __restrict__ gid,
                                                         int* __restrict__ counts) {
    int idx = blockIdx.x * 256 + threadIdx.x;
    if (idx >= B * N / 4) return;
    int b = idx / (N / 4);
    int4 g = reinterpret_cast<const int4*>(gid)[idx];
    int* cb = counts + b * T;
    atomicAdd(&cb[g.x], 1);
    atomicAdd(&cb[g.y], 1);
    atomicAdd(&cb[g.z], 1);
    atomicAdd(&cb[g.w], 1);
}

// ---- exclusive scan counts -> rp [B][T+1]; also seed head = rp ----
__global__ void __launch_bounds__(1024) hemp_scan_kernel(const int* __restrict__ counts,
                                                         int* __restrict__ rp,
                                                         int* __restrict__ head) {
    const int b = blockIdx.x;
    __shared__ int wsum[16];
    __shared__ int carry_s;
    __shared__ int chunk_total_s;
    const int tid = threadIdx.x;
    const int lane = tid & 63;
    const int wv = tid >> 6;
    if (tid == 0) carry_s = 0;
    __syncthreads();
    for (int base = 0; base < T; base += 1024) {
        int i = base + tid;
        int x = (i < T) ? counts[b * T + i] : 0;
        int inc = x;
        #pragma unroll
        for (int off = 1; off < 64; off <<= 1) {
            int y = __shfl_up(inc, off);
            if (lane >= off) inc += y;
        }
        if (lane == 63) wsum[wv] = inc;
        __syncthreads();
        if (wv == 0 && lane < 16) {
            int w = wsum[lane];
            int winc = w;
            #pragma unroll
            for (int off = 1; off < 16; off <<= 1) {
                int y = __shfl_up(winc, off);
                if (lane >= off) winc += y;
            }
            wsum[lane] = winc - w;
            if (lane == 15) chunk_total_s = winc;
        }
        __syncthreads();
        int excl = carry_s + wsum[wv] + (inc - x);
        if (i < T) {
            rp[b * (T + 1) + i] = excl;
            head[b * T + i] = excl;
        }
        __syncthreads();
        if (tid == 0) carry_s += chunk_total_s;
        __syncthreads();
    }
    if (tid == 0) rp[b * (T + 1) + T] = carry_s;  // == N
}

// ---- scatter n into perm (sorted-by-gid order) ----
__global__ void __launch_bounds__(256) hemp_fill_kernel(const int* __restrict__ gid,
                                                        int* __restrict__ head,
                                                        int* __restrict__ perm) {
    int idx = blockIdx.x * 256 + threadIdx.x;  // grid exactly B*N/256
    int b = idx / N;
    int n = idx - b * N;
    int pos = atomicAdd(&head[b * T + gid[idx]], 1);
    perm[(size_t)b * N + pos] = n;
}

// ---- transpose feat [B,C,N] f32 -> featT [B,N,C] bf16 (LDS tiled 64c x 32n) ----
__global__ void __launch_bounds__(256) hemp_tr_kernel(const float* __restrict__ feat,
                                                      ushort* __restrict__ featT) {
    __shared__ float tile[64][33];  // +1 pad: conflict-free transposed reads
    const int blk = blockIdx.x;
    const int b = blk / (1250 * 4);
    const int r = blk - b * (1250 * 4);
    const int nt = r >> 2;        // 0..1249
    const int ct = r & 3;         // 0..3
    const int n0 = nt * 32, c0 = ct * 64;
    const int tid = threadIdx.x;

    const float* __restrict__ fb = feat + (size_t)b * C * N;
    const int nl = tid & 31, c8 = tid >> 5;  // 32 n-lanes x 8 c-rows
    #pragma unroll
    for (int it = 0; it < 8; ++it) {
        int c = c8 + it * 8;
        tile[c][nl] = fb[(size_t)(c0 + c) * N + n0 + nl];
    }
    __syncthreads();

    ushort* __restrict__ ftb = featT + (size_t)b * N * C;
    const int cl = tid & 63, n4 = tid >> 6;  // 64 c-lanes x 4 n-rows
    #pragma unroll
    for (int it = 0; it < 8; ++it) {
        int n = n4 + it * 4;
        float v = tile[cl][n];
        unsigned u = __float_as_uint(v);
        u += 0x7FFFu + ((u >> 16) & 1u);  // round-to-nearest-even bf16
        ftb[(size_t)(n0 + n) * C + c0 + cl] = (ushort)(u >> 16);
    }
}

// ---- pool: block owns GT groups; members are contiguous 512B featT rows ----
static_assert(T % GT == 0, "");
__global__ void __launch_bounds__(256) hemp_pool_kernel(const ushort* __restrict__ featT,
                                                        const int* __restrict__ rp,
                                                        const int* __restrict__ perm,
                                                        float* __restrict__ out) {
    __shared__ float acc[GT][C + 1];  // +1 pad: conflict-free transposed writeout
    const int blk = blockIdx.x;
    const int b = blk / (T / GT);
    const int tt = blk - b * (T / GT);
    const int t0 = tt * GT;
    const int tid = threadIdx.x;
    const int lane = tid & 63, wv = tid >> 6;  // 4 waves, 8 groups each

    const int* __restrict__ rpb = rp + b * (T + 1);
    const int* __restrict__ permb = perm + (size_t)b * N;
    const ushort* __restrict__ ftb = featT + (size_t)b * N * C;

    #pragma unroll
    for (int k = 0; k < GT / 4; ++k) {
        const int g = wv * (GT / 4) + k;
        const int t = t0 + g;
        const int js = rpb[t], je = rpb[t + 1];
        float a0 = 0.f, a1 = 0.f, a2 = 0.f, a3 = 0.f;
        for (int j = js; j < je; ++j) {
            const int m = permb[j];  // wave-uniform -> scalar load
            ushort4 u = *reinterpret_cast<const ushort4*>(ftb + (size_t)m * C + lane * 4);
            a0 += __uint_as_float((unsigned)u.x << 16);
            a1 += __uint_as_float((unsigned)u.y << 16);
            a2 += __uint_as_float((unsigned)u.z << 16);
            a3 += __uint_as_float((unsigned)u.w << 16);
        }
        const float inv = 1.0f / fmaxf((float)(je - js), 1.0f);
        acc[g][lane * 4 + 0] = a0 * inv;
        acc[g][lane * 4 + 1] = a1 * inv;
        acc[g][lane * 4 + 2] = a2 * inv;
        acc[g][lane * 4 + 3] = a3 * inv;
    }
    __syncthreads();

    float* __restrict__ ob = out + (size_t)b * C * T + t0;
    for (int idx = tid; idx < GT * C; idx += 256) {
        int ti = idx & (GT - 1);
        int c = idx >> 5;
        ob[(size_t)c * T + ti] = acc[ti][c];  // 128B runs per c
    }
}

// ---- fallback (ws too small): R2 LDS-atomic kernel, 428us ----
static constexpr int BLK = 1024;
__global__ void __launch_bounds__(BLK) hemp_atomic_kernel(const float* __restrict__ feat,
                                                          const int* __restrict__ gid,
                                                          const int* __restrict__ counts,
                                                          float* __restrict__ out) {
    extern __shared__ float lds_sum[];
    const int tid = threadIdx.x;
    const int b = blockIdx.x >> 8;
    const int c = blockIdx.x & 255;
    float4* ls4 = reinterpret_cast<float4*>(lds_sum);
    for (int t = tid; t < T / 4; t += BLK) ls4[t] = make_float4(0.f, 0.f, 0.f, 0.f);
    __syncthreads();
    const float4* f4 = reinterpret_cast<const float4*>(feat + (size_t)(b * C + c) * N);
    const int4* g4 = reinterpret_cast<const int4*>(gid + (size_t)b * N);
    for (int i = tid; i < N / 4; i += BLK) {
        float4 v = f4[i];
        int4 g = g4[i];
        unsafeAtomicAdd(&lds_sum[g.x], v.x);
        unsafeAtomicAdd(&lds_sum[g.y], v.y);
        unsafeAtomicAdd(&lds_sum[g.z], v.z);
        unsafeAtomicAdd(&lds_sum[g.w], v.w);
    }
    __syncthreads();
    const int4* cnt4 = reinterpret_cast<const int4*>(counts + (size_t)b * T);
    float4* out4 = reinterpret_cast<float4*>(out + (size_t)(b * C + c) * T);
    for (int t = tid; t < T / 4; t += BLK) {
        int4 cn = cnt4[t];
        float4 s = ls4[t];
        float4 r;
        r.x = s.x / fmaxf((float)cn.x, 1.0f);
        r.y = s.y / fmaxf((float)cn.y, 1.0f);
        r.z = s.z / fmaxf((float)cn.z, 1.0f);
        r.w = s.w / fmaxf((float)cn.w, 1.0f);
        out4[t] = r;
    }
}

extern "C" void kernel_launch(void* const* d_in, const int* in_sizes, int n_in,
                              void* d_out, int out_size, void* d_ws, size_t ws_size,
                              hipStream_t stream) {
    const float* feat = (const float*)d_in[0];
    const int* gid = (const int*)d_in[1];
    float* out = (float*)d_out;

    // ws layout: counts[B*T] rp[B*(T+1)] head[B*T] perm[B*N] | featT[B*N*C] bf16
    int* counts = (int*)d_ws;
    int* rp = counts + (size_t)B * T;
    int* head = rp + (size_t)B * (T + 1);
    int* perm = head + (size_t)B * T;
    size_t int_bytes = ((size_t)(B * T) + B * (T + 1) + B * T + (size_t)B * N) * 4;
    size_t featT_off = (int_bytes + 511) & ~(size_t)511;
    size_t need = featT_off + (size_t)B * N * C * 2;

    hipMemsetAsync(counts, 0, (size_t)B * T * sizeof(int), stream);
    hemp_count_kernel<<<(B * N / 4 + 255) / 256, 256, 0, stream>>>(gid, counts);

    if (ws_size >= need) {
        ushort* featT = (ushort*)((char*)d_ws + featT_off);
        hemp_scan_kernel<<<B, 1024, 0, stream>>>(counts, rp, head);
        hemp_fill_kernel<<<B * N / 256, 256, 0, stream>>>(gid, head, perm);
        hemp_tr_kernel<<<B * 1250 * 4, 256, 0, stream>>>(feat, featT);
        hemp_pool_kernel<<<B * (T / GT), 256, 0, stream>>>(featT, rp, perm, out);
    } else {
        const size_t lds_bytes = (size_t)T * sizeof(float);
        hipFuncSetAttribute(reinterpret_cast<const void*>(hemp_atomic_kernel),
                            hipFuncAttributeMaxDynamicSharedMemorySize, (int)lds_bytes);
        hemp_atomic_kernel<<<B * C, BLK, lds_bytes, stream>>>(feat, gid, counts, out);
    }
}

// Round 5
// 252.088 us; speedup vs baseline: 7.0483x; 1.2236x over previous
//
#include <hip/hip_runtime.h>

// HalfEdgeMeshPool: segment-mean over groups.
// feat: [B, C, N] f32, gid: [B, N] i32 in [0,T), out: [B, C, T] f32.
//
// R1/R2: LDS f32 atomics serialize at ~3.2 cyc/lane (occupancy-independent) -> 428us floor.
// R3: random 4B global gather = 14.5x line over-fetch -> 1.7ms.
// R4: sort + transpose-to-[B,N,C]-bf16 + 512B-row gather -> 308us (tr was scalar-access bound).
// R5: fuse reorder into transpose (featT written in sorted order -> pool reads sequentially),
//     float4/dwordx4 everywhere, own zero kernel, int4 scan.
static constexpr int B = 8;
static constexpr int C = 256;
static constexpr int N = 40000;      // 625 tiles of 64
static constexpr int T = 20000;
static constexpr int GT = 32;        // groups per pool block (T/GT = 625)
static constexpr int RPS = T + 4;    // rp row stride (keeps int4 alignment per b)

__device__ __forceinline__ ushort f2bf(float v) {
    unsigned u = __float_as_uint(v);
    u += 0x7FFFu + ((u >> 16) & 1u);  // round-to-nearest-even
    return (ushort)(u >> 16);
}
__device__ __forceinline__ float bf2f(ushort u) {
    return __uint_as_float((unsigned)u << 16);
}

// ---- zero counts (replaces rocclr fill inside the graph) ----
__global__ void __launch_bounds__(256) hemp_zero_kernel(int* __restrict__ counts) {
    int i = blockIdx.x * 256 + threadIdx.x;
    if (i < B * T / 4) reinterpret_cast<int4*>(counts)[i] = make_int4(0, 0, 0, 0);
}

// ---- per-(b,t) member counts ----
__global__ void __launch_bounds__(256) hemp_count_kernel(const int* __restrict__ gid,
                                                         int* __restrict__ counts) {
    int idx = blockIdx.x * 256 + threadIdx.x;
    if (idx >= B * N / 4) return;
    int b = idx / (N / 4);
    int i4 = idx - b * (N / 4);
    int4 g = reinterpret_cast<const int4*>(gid + (size_t)b * N)[i4];
    int* cb = counts + b * T;
    atomicAdd(&cb[g.x], 1);
    atomicAdd(&cb[g.y], 1);
    atomicAdd(&cb[g.z], 1);
    atomicAdd(&cb[g.w], 1);
}

// ---- exclusive scan counts -> rp [B][RPS]; seed head = rp (int4-wide, 5 iters) ----
__global__ void __launch_bounds__(1024) hemp_scan_kernel(const int* __restrict__ counts,
                                                         int* __restrict__ rp,
                                                         int* __restrict__ head) {
    const int b = blockIdx.x;
    __shared__ int wsum[16];
    __shared__ int carry_s, chunk_total_s;
    const int tid = threadIdx.x, lane = tid & 63, wv = tid >> 6;
    if (tid == 0) carry_s = 0;
    __syncthreads();
    const int4* c4 = reinterpret_cast<const int4*>(counts + (size_t)b * T);
    int4* rp4 = reinterpret_cast<int4*>(rp + (size_t)b * RPS);
    int4* hd4 = reinterpret_cast<int4*>(head + (size_t)b * T);
    constexpr int NI4 = T / 4;  // 5000
    for (int base = 0; base < NI4; base += 1024) {
        int i = base + tid;
        int4 x = (i < NI4) ? c4[i] : make_int4(0, 0, 0, 0);
        int s = x.x + x.y + x.z + x.w;
        int inc = s;
        #pragma unroll
        for (int off = 1; off < 64; off <<= 1) {
            int y = __shfl_up(inc, off);
            if (lane >= off) inc += y;
        }
        if (lane == 63) wsum[wv] = inc;
        __syncthreads();
        if (wv == 0 && lane < 16) {
            int w = wsum[lane];
            int winc = w;
            #pragma unroll
            for (int off = 1; off < 16; off <<= 1) {
                int y = __shfl_up(winc, off);
                if (lane >= off) winc += y;
            }
            wsum[lane] = winc - w;
            if (lane == 15) chunk_total_s = winc;
        }
        __syncthreads();
        int e = carry_s + wsum[wv] + (inc - s);
        if (i < NI4) {
            int4 r;
            r.x = e;
            r.y = e + x.x;
            r.z = r.y + x.y;
            r.w = r.z + x.z;
            rp4[i] = r;
            hd4[i] = r;
        }
        __syncthreads();
        if (tid == 0) carry_s += chunk_total_s;
        __syncthreads();
    }
    if (tid == 0) rp[(size_t)b * RPS + T] = N;
}

// ---- rank of each half-edge within sorted-by-group order ----
__global__ void __launch_bounds__(256) hemp_fill_kernel(const int* __restrict__ gid,
                                                        int* __restrict__ head,
                                                        int* __restrict__ rnk) {
    int idx = blockIdx.x * 256 + threadIdx.x;
    if (idx >= B * N / 4) return;
    int b = idx / (N / 4);
    int i4 = idx - b * (N / 4);
    int4 g = reinterpret_cast<const int4*>(gid + (size_t)b * N)[i4];
    int* hb = head + b * T;
    int4 r;
    r.x = atomicAdd(&hb[g.x], 1);
    r.y = atomicAdd(&hb[g.y], 1);
    r.z = atomicAdd(&hb[g.z], 1);
    r.w = atomicAdd(&hb[g.w], 1);
    reinterpret_cast<int4*>(rnk + (size_t)b * N)[i4] = r;
}

// ---- transpose + reorder: feat [C,N] f32 -> featT[rnk(n)][C] bf16 (512B rows) ----
__global__ void __launch_bounds__(256) hemp_tr_kernel(const float* __restrict__ feat,
                                                      const int* __restrict__ rnk,
                                                      ushort* __restrict__ featT) {
    __shared__ ushort tile[64][C + 8];  // row stride 528 B (16B multiple)
    __shared__ int rk[64];
    const int blk = blockIdx.x;  // b*625 + nt
    const int b = blk / 625;
    const int nt = blk - b * 625;
    const int n0 = nt * 64;
    const int tid = threadIdx.x;
    if (tid < 64) rk[tid] = rnk[(size_t)b * N + n0 + tid];

    const float* __restrict__ fb = feat + (size_t)b * C * N;
    const int nl = tid & 15, cg = tid >> 4;  // 16 float4-lanes (64 n) x 16 c per iter
    #pragma unroll
    for (int it = 0; it < 16; ++it) {
        int c = it * 16 + cg;
        float4 v = *reinterpret_cast<const float4*>(fb + (size_t)c * N + n0 + nl * 4);
        tile[nl * 4 + 0][c] = f2bf(v.x);
        tile[nl * 4 + 1][c] = f2bf(v.y);
        tile[nl * 4 + 2][c] = f2bf(v.z);
        tile[nl * 4 + 3][c] = f2bf(v.w);
    }
    __syncthreads();

    ushort* __restrict__ ftb = featT + (size_t)b * N * C;
    const int l32 = tid & 31, r8 = tid >> 5;  // 32 lanes x 16B = one 512B row; 8 rows/round
    #pragma unroll
    for (int rd = 0; rd < 8; ++rd) {
        int row = rd * 8 + r8;
        int4 d = *reinterpret_cast<const int4*>(&tile[row][l32 * 8]);
        *reinterpret_cast<int4*>(ftb + (size_t)rk[row] * C + l32 * 8) = d;
    }
}

// ---- pool: sequential segmented reduction over sorted featT rows ----
static_assert(T % GT == 0, "");
__global__ void __launch_bounds__(256) hemp_pool_kernel(const ushort* __restrict__ featT,
                                                        const int* __restrict__ rp,
                                                        float* __restrict__ out) {
    __shared__ float acc[GT][C + 1];  // +1: conflict-free transposed readout
    const int blk = blockIdx.x;  // b*625 + tt
    const int b = blk / (T / GT);
    const int tt = blk - b * (T / GT);
    const int t0 = tt * GT;
    const int tid = threadIdx.x, lane = tid & 63, wv = tid >> 6;
    const int* __restrict__ rpb = rp + (size_t)b * RPS;
    const ushort* __restrict__ ftb = featT + (size_t)b * N * C;

    #pragma unroll
    for (int k = 0; k < GT / 4; ++k) {
        const int g = wv * (GT / 4) + k;
        const int t = t0 + g;
        const int js = rpb[t], je = rpb[t + 1];
        float a0 = 0.f, a1 = 0.f, a2 = 0.f, a3 = 0.f;
        for (int j = js; j < je; ++j) {  // rows contiguous: pure streaming
            ushort4 u = *reinterpret_cast<const ushort4*>(ftb + (size_t)j * C + lane * 4);
            a0 += bf2f(u.x);
            a1 += bf2f(u.y);
            a2 += bf2f(u.z);
            a3 += bf2f(u.w);
        }
        const float inv = 1.0f / fmaxf((float)(je - js), 1.0f);
        acc[g][lane * 4 + 0] = a0 * inv;
        acc[g][lane * 4 + 1] = a1 * inv;
        acc[g][lane * 4 + 2] = a2 * inv;
        acc[g][lane * 4 + 3] = a3 * inv;
    }
    __syncthreads();

    float* __restrict__ ob = out + (size_t)b * C * T + t0;
    const int l32 = tid & 31, c8 = tid >> 5;
    #pragma unroll
    for (int rd = 0; rd < 32; ++rd) {
        int c = rd * 8 + c8;
        ob[(size_t)c * T + l32] = acc[l32][c];  // 128B contiguous per c
    }
}

// ---- fallback (ws too small): R2 LDS-atomic kernel ----
static constexpr int BLK = 1024;
__global__ void __launch_bounds__(BLK) hemp_atomic_kernel(const float* __restrict__ feat,
                                                          const int* __restrict__ gid,
                                                          const int* __restrict__ counts,
                                                          float* __restrict__ out) {
    extern __shared__ float lds_sum[];
    const int tid = threadIdx.x;
    const int b = blockIdx.x >> 8;
    const int c = blockIdx.x & 255;
    float4* ls4 = reinterpret_cast<float4*>(lds_sum);
    for (int t = tid; t < T / 4; t += BLK) ls4[t] = make_float4(0.f, 0.f, 0.f, 0.f);
    __syncthreads();
    const float4* f4 = reinterpret_cast<const float4*>(feat + (size_t)(b * C + c) * N);
    const int4* g4 = reinterpret_cast<const int4*>(gid + (size_t)b * N);
    for (int i = tid; i < N / 4; i += BLK) {
        float4 v = f4[i];
        int4 g = g4[i];
        unsafeAtomicAdd(&lds_sum[g.x], v.x);
        unsafeAtomicAdd(&lds_sum[g.y], v.y);
        unsafeAtomicAdd(&lds_sum[g.z], v.z);
        unsafeAtomicAdd(&lds_sum[g.w], v.w);
    }
    __syncthreads();
    const int4* cnt4 = reinterpret_cast<const int4*>(counts + (size_t)b * T);
    float4* out4 = reinterpret_cast<float4*>(out + (size_t)(b * C + c) * T);
    for (int t = tid; t < T / 4; t += BLK) {
        int4 cn = cnt4[t];
        float4 s = ls4[t];
        float4 r;
        r.x = s.x / fmaxf((float)cn.x, 1.0f);
        r.y = s.y / fmaxf((float)cn.y, 1.0f);
        r.z = s.z / fmaxf((float)cn.z, 1.0f);
        r.w = s.w / fmaxf((float)cn.w, 1.0f);
        out4[t] = r;
    }
}

extern "C" void kernel_launch(void* const* d_in, const int* in_sizes, int n_in,
                              void* d_out, int out_size, void* d_ws, size_t ws_size,
                              hipStream_t stream) {
    const float* feat = (const float*)d_in[0];
    const int* gid = (const int*)d_in[1];
    float* out = (float*)d_out;

    // ws: counts[B*T] | head[B*T] | rp[B*RPS] | rnk[B*N] | featT[B*N*C] bf16 (512-aligned)
    int* counts = (int*)d_ws;
    int* head = counts + (size_t)B * T;
    int* rp = head + (size_t)B * T;
    int* rnk = rp + (size_t)B * RPS;
    size_t int_bytes = ((size_t)B * T * 2 + (size_t)B * RPS + (size_t)B * N) * 4;
    size_t featT_off = (int_bytes + 511) & ~(size_t)511;
    size_t need = featT_off + (size_t)B * N * C * 2;

    hemp_zero_kernel<<<(B * T / 4 + 255) / 256, 256, 0, stream>>>(counts);
    hemp_count_kernel<<<(B * N / 4 + 255) / 256, 256, 0, stream>>>(gid, counts);

    if (ws_size >= need) {
        ushort* featT = (ushort*)((char*)d_ws + featT_off);
        hemp_scan_kernel<<<B, 1024, 0, stream>>>(counts, rp, head);
        hemp_fill_kernel<<<(B * N / 4 + 255) / 256, 256, 0, stream>>>(gid, head, rnk);
        hemp_tr_kernel<<<B * 625, 256, 0, stream>>>(feat, rnk, featT);
        hemp_pool_kernel<<<B * (T / GT), 256, 0, stream>>>(featT, rp, out);
    } else {
        const size_t lds_bytes = (size_t)T * sizeof(float);
        hipFuncSetAttribute(reinterpret_cast<const void*>(hemp_atomic_kernel),
                            hipFuncAttributeMaxDynamicSharedMemorySize, (int)lds_bytes);
        hemp_atomic_kernel<<<B * C, BLK, lds_bytes, stream>>>(feat, gid, counts, out);
    }
}

// Round 6
// 249.822 us; speedup vs baseline: 7.1123x; 1.0091x over previous
//
#include <hip/hip_runtime.h>

// HalfEdgeMeshPool: segment-mean over groups.
// feat: [B, C, N] f32, gid: [B, N] i32 in [0,T), out: [B, C, T] f32.
//
// R1/R2: LDS f32 atomics serialize ~3.2 cyc/lane -> 428us floor. R3: random 4B
// gather = 14.5x over-fetch. R5: sort + transpose-to-[B,N,C]-bf16 + sequential
// row reduce -> 252us, but tr's transposing u16 LDS stores were 16-32-way
// bank-conflicted (528-byte row stride: bank = 16*lane mod 32) = LDS-bound.
// R6: 128x256 tiles, in-register 4x4 transpose -> u16x4 LDS stores + 16B-chunk
// XOR swizzle (<=8-way, 4x fewer stores); 512B global read bursts; pool with
// streamed prefetch segmented reduction; nontemporal hot-path accesses.
static constexpr int B = 8;
static constexpr int C = 256;
static constexpr int N = 40000;
static constexpr int T = 20000;
static constexpr int GT = 32;        // groups per pool block (T/GT = 625)
static constexpr int RPS = T + 4;    // rp row stride (int4 alignment per b)
static constexpr int NTILE = 128;
static constexpr int NT_B = (N + NTILE - 1) / NTILE;  // 313 (last tile = 64 rows)

typedef float  f32x4 __attribute__((ext_vector_type(4)));
typedef int    i32x4 __attribute__((ext_vector_type(4)));
typedef ushort u16x4 __attribute__((ext_vector_type(4)));

__device__ __forceinline__ ushort f2bf(float v) {
    unsigned u = __float_as_uint(v);
    u += 0x7FFFu + ((u >> 16) & 1u);  // round-to-nearest-even
    return (ushort)(u >> 16);
}
__device__ __forceinline__ float bf2f(ushort u) {
    return __uint_as_float((unsigned)u << 16);
}

// ---- zero counts ----
__global__ void __launch_bounds__(256) hemp_zero_kernel(int* __restrict__ counts) {
    int i = blockIdx.x * 256 + threadIdx.x;
    if (i < B * T / 4) reinterpret_cast<int4*>(counts)[i] = make_int4(0, 0, 0, 0);
}

// ---- per-(b,t) member counts ----
__global__ void __launch_bounds__(256) hemp_count_kernel(const int* __restrict__ gid,
                                                         int* __restrict__ counts) {
    int idx = blockIdx.x * 256 + threadIdx.x;
    if (idx >= B * N / 4) return;
    int b = idx / (N / 4);
    int i4 = idx - b * (N / 4);
    int4 g = reinterpret_cast<const int4*>(gid + (size_t)b * N)[i4];
    int* cb = counts + b * T;
    atomicAdd(&cb[g.x], 1);
    atomicAdd(&cb[g.y], 1);
    atomicAdd(&cb[g.z], 1);
    atomicAdd(&cb[g.w], 1);
}

// ---- exclusive scan counts -> rp [B][RPS]; seed head = rp ----
__global__ void __launch_bounds__(1024) hemp_scan_kernel(const int* __restrict__ counts,
                                                         int* __restrict__ rp,
                                                         int* __restrict__ head) {
    const int b = blockIdx.x;
    __shared__ int wsum[16];
    __shared__ int carry_s, chunk_total_s;
    const int tid = threadIdx.x, lane = tid & 63, wv = tid >> 6;
    if (tid == 0) carry_s = 0;
    __syncthreads();
    const int4* c4 = reinterpret_cast<const int4*>(counts + (size_t)b * T);
    int4* rp4 = reinterpret_cast<int4*>(rp + (size_t)b * RPS);
    int4* hd4 = reinterpret_cast<int4*>(head + (size_t)b * T);
    constexpr int NI4 = T / 4;  // 5000
    for (int base = 0; base < NI4; base += 1024) {
        int i = base + tid;
        int4 x = (i < NI4) ? c4[i] : make_int4(0, 0, 0, 0);
        int s = x.x + x.y + x.z + x.w;
        int inc = s;
        #pragma unroll
        for (int off = 1; off < 64; off <<= 1) {
            int y = __shfl_up(inc, off);
            if (lane >= off) inc += y;
        }
        if (lane == 63) wsum[wv] = inc;
        __syncthreads();
        if (wv == 0 && lane < 16) {
            int w = wsum[lane];
            int winc = w;
            #pragma unroll
            for (int off = 1; off < 16; off <<= 1) {
                int y = __shfl_up(winc, off);
                if (lane >= off) winc += y;
            }
            wsum[lane] = winc - w;
            if (lane == 15) chunk_total_s = winc;
        }
        __syncthreads();
        int e = carry_s + wsum[wv] + (inc - s);
        if (i < NI4) {
            int4 r;
            r.x = e;
            r.y = e + x.x;
            r.z = r.y + x.y;
            r.w = r.z + x.z;
            rp4[i] = r;
            hd4[i] = r;
        }
        __syncthreads();
        if (tid == 0) carry_s += chunk_total_s;
        __syncthreads();
    }
    if (tid == 0) rp[(size_t)b * RPS + T] = N;
}

// ---- rank of each half-edge within sorted-by-group order ----
__global__ void __launch_bounds__(256) hemp_fill_kernel(const int* __restrict__ gid,
                                                        int* __restrict__ head,
                                                        int* __restrict__ rnk) {
    int idx = blockIdx.x * 256 + threadIdx.x;
    if (idx >= B * N / 4) return;
    int b = idx / (N / 4);
    int i4 = idx - b * (N / 4);
    int4 g = reinterpret_cast<const int4*>(gid + (size_t)b * N)[i4];
    int* hb = head + b * T;
    int4 r;
    r.x = atomicAdd(&hb[g.x], 1);
    r.y = atomicAdd(&hb[g.y], 1);
    r.z = atomicAdd(&hb[g.z], 1);
    r.w = atomicAdd(&hb[g.w], 1);
    reinterpret_cast<int4*>(rnk + (size_t)b * N)[i4] = r;
}

// ---- transpose+reorder: feat [C,N] f32 -> featT[rnk(n)][C] bf16 ----
// 128n x 256c tile, 512 threads. In-register 4x4 transpose -> u16x4 LDS stores.
// LDS layout: row-major stride 256 u16, 16B chunks XOR-swizzled by (row>>2)&7.
__global__ void __launch_bounds__(512) hemp_tr_kernel(const float* __restrict__ feat,
                                                      const int* __restrict__ rnk,
                                                      ushort* __restrict__ featT) {
    __shared__ ushort tile[NTILE * 256];  // 64 KB, no pad (XOR swizzle)
    __shared__ int rk[NTILE];
    const int blk = blockIdx.x;  // b*NT_B + nt
    const int b = blk / NT_B;
    const int nt = blk - b * NT_B;
    const int n0 = nt * NTILE;
    const int nrows = min(NTILE, N - n0);  // 64 on the last tile
    const int tid = threadIdx.x;
    if (tid < nrows) rk[tid] = rnk[(size_t)b * N + n0 + tid];

    const float* __restrict__ fb = feat + (size_t)b * C * N;
    const int l32 = tid & 31, grp = tid >> 5;  // 16 groups of 32 lanes
    const int nr = l32 * 4;                    // this lane's 4 tile rows
    if (nr < nrows) {
        const int key = l32 & 7;  // == (row>>2)&7 for rows nr..nr+3
        #pragma unroll
        for (int m = 0; m < 4; ++m) {
            const int c0 = grp * 16 + m * 4;
            f32x4 v0 = *(const f32x4*)(fb + (size_t)(c0 + 0) * N + n0 + nr);
            f32x4 v1 = *(const f32x4*)(fb + (size_t)(c0 + 1) * N + n0 + nr);
            f32x4 v2 = *(const f32x4*)(fb + (size_t)(c0 + 2) * N + n0 + nr);
            f32x4 v3 = *(const f32x4*)(fb + (size_t)(c0 + 3) * N + n0 + nr);
            const int chunk_off = (((c0 >> 3) ^ key) << 3) | (c0 & 7);
            #pragma unroll
            for (int r = 0; r < 4; ++r) {
                u16x4 w;
                w.x = f2bf(v0[r]);
                w.y = f2bf(v1[r]);
                w.z = f2bf(v2[r]);
                w.w = f2bf(v3[r]);
                *(u16x4*)&tile[(nr + r) * 256 + chunk_off] = w;
            }
        }
    }
    __syncthreads();

    ushort* __restrict__ ftb = featT + (size_t)b * N * C;
    #pragma unroll
    for (int rd = 0; rd < 8; ++rd) {
        const int row = rd * 16 + grp;
        if (row < nrows) {
            i32x4 d = *(const i32x4*)&tile[row * 256 + l32 * 8];  // phys chunk l32
            const int lc = (l32 ^ ((row >> 2) & 7)) * 8;          // logical c base
            __builtin_nontemporal_store(d, (i32x4*)(ftb + (size_t)rk[row] * C + lc));
        }
    }
}

// ---- pool: streamed segmented reduction over sorted rows, depth-1 prefetch ----
static_assert(T % GT == 0, "");
__global__ void __launch_bounds__(256) hemp_pool_kernel(const ushort* __restrict__ featT,
                                                        const int* __restrict__ rp,
                                                        float* __restrict__ out) {
    __shared__ float acc[GT][C + 1];
    const int blk = blockIdx.x;  // b*625 + tt
    const int b = blk / (T / GT);
    const int tt = blk - b * (T / GT);
    const int t0 = tt * GT;
    const int tid = threadIdx.x, lane = tid & 63, wv = tid >> 6;
    const int tw = t0 + wv * 8;  // wave owns 8 groups
    const int* __restrict__ rpb = rp + (size_t)b * RPS;
    const ushort* __restrict__ ftb = featT + (size_t)b * N * C;

    int j = rpb[tw];
    const int jend = rpb[tw + 8];
    int g = 0;
    int gend = rpb[tw + 1];
    float a0 = 0.f, a1 = 0.f, a2 = 0.f, a3 = 0.f;
    int cnt = 0;
    u16x4 cur = {};
    if (j < jend)
        cur = __builtin_nontemporal_load((const u16x4*)(ftb + (size_t)j * C + lane * 4));
    while (true) {
        while (g < 8 && j == gend) {  // flush finished (possibly empty) groups
            const float inv = 1.0f / fmaxf((float)cnt, 1.0f);
            const int gg = wv * 8 + g;
            acc[gg][lane * 4 + 0] = a0 * inv;
            acc[gg][lane * 4 + 1] = a1 * inv;
            acc[gg][lane * 4 + 2] = a2 * inv;
            acc[gg][lane * 4 + 3] = a3 * inv;
            a0 = a1 = a2 = a3 = 0.f;
            cnt = 0;
            ++g;
            if (g < 8) gend = rpb[tw + g + 1];
        }
        if (j >= jend) break;
        u16x4 nxt = cur;
        if (j + 1 < jend)
            nxt = __builtin_nontemporal_load((const u16x4*)(ftb + (size_t)(j + 1) * C + lane * 4));
        a0 += bf2f(cur.x);
        a1 += bf2f(cur.y);
        a2 += bf2f(cur.z);
        a3 += bf2f(cur.w);
        ++cnt;
        ++j;
        cur = nxt;
    }
    while (g < 8) {  // safety: trailing empty groups
        const int gg = wv * 8 + g;
        acc[gg][lane * 4 + 0] = 0.f;
        acc[gg][lane * 4 + 1] = 0.f;
        acc[gg][lane * 4 + 2] = 0.f;
        acc[gg][lane * 4 + 3] = 0.f;
        ++g;
    }
    __syncthreads();

    float* __restrict__ ob = out + (size_t)b * C * T + t0;
    const int l32 = tid & 31, c8 = tid >> 5;
    #pragma unroll
    for (int rd = 0; rd < 32; ++rd) {
        int c = rd * 8 + c8;
        __builtin_nontemporal_store(acc[l32][c], ob + (size_t)c * T + l32);
    }
}

// ---- fallback (ws too small): R2 LDS-atomic kernel ----
static constexpr int BLK = 1024;
__global__ void __launch_bounds__(BLK) hemp_atomic_kernel(const float* __restrict__ feat,
                                                          const int* __restrict__ gid,
                                                          const int* __restrict__ counts,
                                                          float* __restrict__ out) {
    extern __shared__ float lds_sum[];
    const int tid = threadIdx.x;
    const int b = blockIdx.x >> 8;
    const int c = blockIdx.x & 255;
    float4* ls4 = reinterpret_cast<float4*>(lds_sum);
    for (int t = tid; t < T / 4; t += BLK) ls4[t] = make_float4(0.f, 0.f, 0.f, 0.f);
    __syncthreads();
    const float4* f4 = reinterpret_cast<const float4*>(feat + (size_t)(b * C + c) * N);
    const int4* g4 = reinterpret_cast<const int4*>(gid + (size_t)b * N);
    for (int i = tid; i < N / 4; i += BLK) {
        float4 v = f4[i];
        int4 g = g4[i];
        unsafeAtomicAdd(&lds_sum[g.x], v.x);
        unsafeAtomicAdd(&lds_sum[g.y], v.y);
        unsafeAtomicAdd(&lds_sum[g.z], v.z);
        unsafeAtomicAdd(&lds_sum[g.w], v.w);
    }
    __syncthreads();
    const int4* cnt4 = reinterpret_cast<const int4*>(counts + (size_t)b * T);
    float4* out4 = reinterpret_cast<float4*>(out + (size_t)(b * C + c) * T);
    for (int t = tid; t < T / 4; t += BLK) {
        int4 cn = cnt4[t];
        float4 s = ls4[t];
        float4 r;
        r.x = s.x / fmaxf((float)cn.x, 1.0f);
        r.y = s.y / fmaxf((float)cn.y, 1.0f);
        r.z = s.z / fmaxf((float)cn.z, 1.0f);
        r.w = s.w / fmaxf((float)cn.w, 1.0f);
        out4[t] = r;
    }
}

extern "C" void kernel_launch(void* const* d_in, const int* in_sizes, int n_in,
                              void* d_out, int out_size, void* d_ws, size_t ws_size,
                              hipStream_t stream) {
    const float* feat = (const float*)d_in[0];
    const int* gid = (const int*)d_in[1];
    float* out = (float*)d_out;

    // ws: counts[B*T] | head[B*T] | rp[B*RPS] | rnk[B*N] | featT[B*N*C] bf16
    int* counts = (int*)d_ws;
    int* head = counts + (size_t)B * T;
    int* rp = head + (size_t)B * T;
    int* rnk = rp + (size_t)B * RPS;
    size_t int_bytes = ((size_t)B * T * 2 + (size_t)B * RPS + (size_t)B * N) * 4;
    size_t featT_off = (int_bytes + 511) & ~(size_t)511;
    size_t need = featT_off + (size_t)B * N * C * 2;

    hemp_zero_kernel<<<(B * T / 4 + 255) / 256, 256, 0, stream>>>(counts);
    hemp_count_kernel<<<(B * N / 4 + 255) / 256, 256, 0, stream>>>(gid, counts);

    if (ws_size >= need) {
        ushort* featT = (ushort*)((char*)d_ws + featT_off);
        hemp_scan_kernel<<<B, 1024, 0, stream>>>(counts, rp, head);
        hemp_fill_kernel<<<(B * N / 4 + 255) / 256, 256, 0, stream>>>(gid, head, rnk);
        hemp_tr_kernel<<<B * NT_B, 512, 0, stream>>>(feat, rnk, featT);
        hemp_pool_kernel<<<B * (T / GT), 256, 0, stream>>>(featT, rp, out);
    } else {
        const size_t lds_bytes = (size_t)T * sizeof(float);
        hipFuncSetAttribute(reinterpret_cast<const void*>(hemp_atomic_kernel),
                            hipFuncAttributeMaxDynamicSharedMemorySize, (int)lds_bytes);
        hemp_atomic_kernel<<<B * C, BLK, lds_bytes, stream>>>(feat, gid, counts, out);
    }
}